// Round 2
// baseline (506.951 us; speedup 1.0000x reference)
//
#include <hip/hip_runtime.h>
#include <hip/hip_bf16.h>
#include <cstdint>
#include <cstddef>

#define B_DIM 2
#define H_DIM 8
#define S_DIM 2048
#define D_DIM 512
#define BH_DIM 16
#define INV_TEMP 0.044194173824159216f
#define LN_EPS 1e-5f

typedef __attribute__((ext_vector_type(8))) __bf16 bf16x8;
typedef __attribute__((ext_vector_type(4))) float floatx4;

static __device__ __forceinline__ __bf16 to_bf16(float f) {
    unsigned u = __builtin_bit_cast(unsigned, f);
    u += 0x7fffu + ((u >> 16) & 1u);
    unsigned short h = (unsigned short)(u >> 16);
    return __builtin_bit_cast(__bf16, h);
}

static __device__ __forceinline__ floatx4 mfma_bf16(bf16x8 a, bf16x8 b, floatx4 c) {
    return __builtin_amdgcn_mfma_f32_16x16x32_bf16(a, b, c, 0, 0, 0);
}

// ---------------------------------------------------------------------------
// Kernel 1: QKV projections. out = x @ W^T + bias.
//   z=0: Q' = (q Wq^T + bq)/TEMP  -> Qs [BH][S][64] bf16
//   z=1: K' =  k Wk^T + bk        -> Ks [BH][S][64] bf16
//   z=2: V'^T (transposed)        -> Vt [BH][64][S] bf16
// 128x128 tile per block, BK=64, 4 waves each 64x64 (4x4 of 16x16x32 MFMA).
// ---------------------------------------------------------------------------
__global__ __launch_bounds__(256) void qkv_gemm(
    const float* __restrict__ q, const float* __restrict__ k, const float* __restrict__ v,
    const float* __restrict__ Wq, const float* __restrict__ bq,
    const float* __restrict__ Wk, const float* __restrict__ bk,
    const float* __restrict__ Wv, const float* __restrict__ bv,
    __bf16* __restrict__ Qs, __bf16* __restrict__ Ks, __bf16* __restrict__ Vt)
{
    const int z = blockIdx.z;
    const float* xin  = (z == 0) ? q  : (z == 1) ? k  : v;
    const float* W    = (z == 0) ? Wq : (z == 1) ? Wk : Wv;
    const float* bias = (z == 0) ? bq : (z == 1) ? bk : bv;

    __shared__ __bf16 As[128 * 72];   // stride 72: 144B rows -> 16B-aligned b128, 2-way banks
    __shared__ __bf16 Bs[128 * 72];

    const int tid = threadIdx.x;
    const int m0 = blockIdx.x * 128;
    const int n0 = blockIdx.y * 128;
    const int wave = tid >> 6, lane = tid & 63;
    const int lr = lane & 15, lq = lane >> 4;
    const int wm = (wave & 1) * 64, wn = (wave >> 1) * 64;

    floatx4 acc[4][4] = {};

    for (int k0 = 0; k0 < 512; k0 += 64) {
        for (int i = 0; i < 8; i++) {
            int idx = tid + i * 256;
            int row = idx >> 4, c4 = (idx & 15) * 4;
            float4 a = *(const float4*)(xin + (size_t)(m0 + row) * 512 + k0 + c4);
            __bf16* da = &As[row * 72 + c4];
            da[0] = to_bf16(a.x); da[1] = to_bf16(a.y); da[2] = to_bf16(a.z); da[3] = to_bf16(a.w);
            float4 w4 = *(const float4*)(W + (size_t)(n0 + row) * 512 + k0 + c4);
            __bf16* db = &Bs[row * 72 + c4];
            db[0] = to_bf16(w4.x); db[1] = to_bf16(w4.y); db[2] = to_bf16(w4.z); db[3] = to_bf16(w4.w);
        }
        __syncthreads();
        for (int kk = 0; kk < 64; kk += 32) {
            bf16x8 af[4], bfr[4];
            for (int mi = 0; mi < 4; mi++)
                af[mi] = *(const bf16x8*)&As[(wm + mi * 16 + lr) * 72 + kk + lq * 8];
            for (int ni = 0; ni < 4; ni++)
                bfr[ni] = *(const bf16x8*)&Bs[(wn + ni * 16 + lr) * 72 + kk + lq * 8];
            for (int mi = 0; mi < 4; mi++)
                for (int ni = 0; ni < 4; ni++)
                    acc[mi][ni] = mfma_bf16(af[mi], bfr[ni], acc[mi][ni]);
        }
        __syncthreads();
    }

    // Epilogue. D layout: row = lq*4+r, col = lr (verified m89/m91).
    for (int ni = 0; ni < 4; ni++) {
        int gn = n0 + wn + ni * 16 + lr;
        float bb = bias[gn];
        int h = gn >> 6, dd = gn & 63;
        for (int mi = 0; mi < 4; mi++) {
            for (int r = 0; r < 4; r++) {
                int gm = m0 + wm + mi * 16 + lq * 4 + r;
                int bat = gm >> 11, s = gm & 2047;
                int bh = bat * 8 + h;
                float val = acc[mi][ni][r] + bb;
                if (z == 0)      Qs[((size_t)bh * S_DIM + s) * 64 + dd] = to_bf16(val * INV_TEMP);
                else if (z == 1) Ks[((size_t)bh * S_DIM + s) * 64 + dd] = to_bf16(val);
                else             Vt[((size_t)bh * 64 + dd) * S_DIM + s] = to_bf16(val);
            }
        }
    }
}

// ---------------------------------------------------------------------------
// Kernel 2: attention, v3.
// Block = 32 q rows x full kt, 4 waves (wave pair splits kt in halves).
// XCD-pinned bh: grid flattened to 1024 blocks; hardware round-robins block
// id -> XCD (id & 7). We assign XCD k exactly bh in {2k, 2k+1}, so the
// per-XCD K/V working set is ~1.2 MB (fits the 4 MiB XCD L2) instead of
// 12 MB (all 16 bh) -> K/V stream becomes L2-hit instead of L3-latency.
// V is double-buffered across iterations (was loaded same-iteration,
// an unhidden ~700 cy L3 stall on the PV critical path).
// ---------------------------------------------------------------------------
__global__ __launch_bounds__(256, 4) void attn_kernel(
    const __bf16* __restrict__ Qs, const __bf16* __restrict__ Ks, const __bf16* __restrict__ Vt,
    float* __restrict__ attn_out, __bf16* __restrict__ ctx)
{
    // XCD-aware swizzle: id % 8 = XCD (round-robin dispatch), bijective since
    // 1024 % 8 == 0. XCD k owns bh {2k, 2k+1}; j enumerates 2 bh x 64 qblocks.
    const int id = blockIdx.x;
    const int xcd = id & 7, j = id >> 3;
    const int bh = (xcd << 1) | (j >> 6);
    const int qx = j & 63;
    const int b = bh >> 3, h = bh & 7;

    const int wave = threadIdx.x >> 6, lane = threadIdx.x & 63;
    const int lr = lane & 15, lq = lane >> 4;
    const int pair = wave >> 1, half = wave & 1;
    const int qw = qx * 32 + pair * 16;
    const int kt0 = half * (S_DIM / 2), kt1 = kt0 + (S_DIM / 2);

    const __bf16* Qh = Qs + (size_t)bh * S_DIM * 64;
    const __bf16* Kh = Ks + (size_t)bh * S_DIM * 64;
    const __bf16* Vh = Vt + (size_t)bh * 64 * S_DIM;

    __shared__ float  Ls[4][16];       // per-wave partial row sums
    __shared__ __bf16 Pst[4][16][40];  // per-wave P tile, 16q x 32kp, stride 40
    __shared__ float  Os[2][16][68];   // per-pair O-combine buffer

    // Q A-frags: A[m=lr][k=lq*8+j]; held across both passes.
    bf16x8 aq0 = *(const bf16x8*)(Qh + (size_t)(qw + lr) * 64 + lq * 8);
    bf16x8 aq1 = *(const bf16x8*)(Qh + (size_t)(qw + lr) * 64 + 32 + lq * 8);

    // ---- Pass 1: partial row sums of exp(scores) over [kt0, kt1) ----
    float lsum[4] = {0.f, 0.f, 0.f, 0.f};
    bf16x8 kc0 = *(const bf16x8*)(Kh + (size_t)(kt0 + lr) * 64 + lq * 8);
    bf16x8 kc1 = *(const bf16x8*)(Kh + (size_t)(kt0 + lr) * 64 + 32 + lq * 8);
    bf16x8 kc2 = *(const bf16x8*)(Kh + (size_t)(kt0 + 16 + lr) * 64 + lq * 8);
    bf16x8 kc3 = *(const bf16x8*)(Kh + (size_t)(kt0 + 16 + lr) * 64 + 32 + lq * 8);
    for (int kt = kt0; kt < kt1; kt += 32) {
        const int ktn = (kt + 32 < kt1) ? kt + 32 : kt;
        bf16x8 kn0 = *(const bf16x8*)(Kh + (size_t)(ktn + lr) * 64 + lq * 8);
        bf16x8 kn1 = *(const bf16x8*)(Kh + (size_t)(ktn + lr) * 64 + 32 + lq * 8);
        bf16x8 kn2 = *(const bf16x8*)(Kh + (size_t)(ktn + 16 + lr) * 64 + lq * 8);
        bf16x8 kn3 = *(const bf16x8*)(Kh + (size_t)(ktn + 16 + lr) * 64 + 32 + lq * 8);
        floatx4 s0 = {}, s1 = {};
        s0 = mfma_bf16(aq0, kc0, s0); s0 = mfma_bf16(aq1, kc1, s0);
        s1 = mfma_bf16(aq0, kc2, s1); s1 = mfma_bf16(aq1, kc3, s1);
        for (int r = 0; r < 4; r++) lsum[r] += __expf(s0[r]) + __expf(s1[r]);
        kc0 = kn0; kc1 = kn1; kc2 = kn2; kc3 = kn3;
    }
    // reduce across the 16 lanes of each quad (rows are quad-local)
    for (int m = 1; m < 16; m <<= 1)
        for (int r = 0; r < 4; r++) lsum[r] += __shfl_xor(lsum[r], m);

    // combine the two kt-halves of this wave pair
    if (lr == 0)
        for (int r = 0; r < 4; r++) Ls[wave][lq * 4 + r] = lsum[r];
    __syncthreads();
    float linv[4];
    for (int r = 0; r < 4; r++)
        linv[r] = 1.0f / (lsum[r] + Ls[wave ^ 1][lq * 4 + r]);

    // ---- Pass 2: recompute scores, write normalized attn, accumulate O ----
    floatx4 o[4] = {};
    float* aout = attn_out + ((size_t)(h * B_DIM + b) * S_DIM + qw) * S_DIM;

    kc0 = *(const bf16x8*)(Kh + (size_t)(kt0 + lr) * 64 + lq * 8);
    kc1 = *(const bf16x8*)(Kh + (size_t)(kt0 + lr) * 64 + 32 + lq * 8);
    kc2 = *(const bf16x8*)(Kh + (size_t)(kt0 + 16 + lr) * 64 + lq * 8);
    kc3 = *(const bf16x8*)(Kh + (size_t)(kt0 + 16 + lr) * 64 + 32 + lq * 8);
    bf16x8 vc0 = *(const bf16x8*)(Vh + (size_t)(0 * 16 + lr) * S_DIM + kt0 + lq * 8);
    bf16x8 vc1 = *(const bf16x8*)(Vh + (size_t)(1 * 16 + lr) * S_DIM + kt0 + lq * 8);
    bf16x8 vc2 = *(const bf16x8*)(Vh + (size_t)(2 * 16 + lr) * S_DIM + kt0 + lq * 8);
    bf16x8 vc3 = *(const bf16x8*)(Vh + (size_t)(3 * 16 + lr) * S_DIM + kt0 + lq * 8);

    for (int kt = kt0; kt < kt1; kt += 32) {
        const int ktn = (kt + 32 < kt1) ? kt + 32 : kt;
        // prefetch next iteration's K and V frags
        bf16x8 kn0 = *(const bf16x8*)(Kh + (size_t)(ktn + lr) * 64 + lq * 8);
        bf16x8 kn1 = *(const bf16x8*)(Kh + (size_t)(ktn + lr) * 64 + 32 + lq * 8);
        bf16x8 kn2 = *(const bf16x8*)(Kh + (size_t)(ktn + 16 + lr) * 64 + lq * 8);
        bf16x8 kn3 = *(const bf16x8*)(Kh + (size_t)(ktn + 16 + lr) * 64 + 32 + lq * 8);
        bf16x8 vn0 = *(const bf16x8*)(Vh + (size_t)(0 * 16 + lr) * S_DIM + ktn + lq * 8);
        bf16x8 vn1 = *(const bf16x8*)(Vh + (size_t)(1 * 16 + lr) * S_DIM + ktn + lq * 8);
        bf16x8 vn2 = *(const bf16x8*)(Vh + (size_t)(2 * 16 + lr) * S_DIM + ktn + lq * 8);
        bf16x8 vn3 = *(const bf16x8*)(Vh + (size_t)(3 * 16 + lr) * S_DIM + ktn + lq * 8);

        floatx4 s0 = {}, s1 = {};
        s0 = mfma_bf16(aq0, kc0, s0); s0 = mfma_bf16(aq1, kc1, s0);
        s1 = mfma_bf16(aq0, kc2, s1); s1 = mfma_bf16(aq1, kc3, s1);

        float p0[4], p1[4];
        for (int r = 0; r < 4; r++) {
            p0[r] = __expf(s0[r]) * linv[r];
            p1[r] = __expf(s1[r]) * linv[r];
        }
        // write normalized attn (fp32), 64B segments per row
        for (int r = 0; r < 4; r++) {
            aout[(size_t)(lq * 4 + r) * S_DIM + kt + lr]      = p0[r];
            aout[(size_t)(lq * 4 + r) * S_DIM + kt + 16 + lr] = p1[r];
        }
        // P: C/D layout -> per-wave LDS tile -> A-operand layout (no barrier:
        // same-wave DS ordering + compiler lgkmcnt suffice)
        for (int r = 0; r < 4; r++) {
            Pst[wave][lq * 4 + r][lr]      = to_bf16(p0[r]);
            Pst[wave][lq * 4 + r][lr + 16] = to_bf16(p1[r]);
        }
        bf16x8 pa = *(const bf16x8*)&Pst[wave][lr][lq * 8];
        o[0] = mfma_bf16(pa, vc0, o[0]);
        o[1] = mfma_bf16(pa, vc1, o[1]);
        o[2] = mfma_bf16(pa, vc2, o[2]);
        o[3] = mfma_bf16(pa, vc3, o[3]);

        kc0 = kn0; kc1 = kn1; kc2 = kn2; kc3 = kn3;
        vc0 = vn0; vc1 = vn1; vc2 = vn2; vc3 = vn3;
    }

    // ---- Combine partial O across the wave pair, store ctx ----
    if (half == 1) {
        for (int ni = 0; ni < 4; ni++)
            for (int r = 0; r < 4; r++)
                Os[pair][lq * 4 + r][ni * 16 + lr] = o[ni][r];
    }
    __syncthreads();
    if (half == 0) {
        for (int ni = 0; ni < 4; ni++)
            for (int r = 0; r < 4; r++) {
                float val = o[ni][r] + Os[pair][lq * 4 + r][ni * 16 + lr];
                ctx[((size_t)b * S_DIM + qw + lq * 4 + r) * 512 + h * 64 + ni * 16 + lr] =
                    to_bf16(val);
            }
    }
}

// ---------------------------------------------------------------------------
// Kernel 3: fc projection. fc_out = ctx @ Wfc^T + bfc (fp32 to ws).
// ---------------------------------------------------------------------------
__global__ __launch_bounds__(256) void fc_gemm(
    const __bf16* __restrict__ ctx, const float* __restrict__ Wfc,
    const float* __restrict__ bfc, float* __restrict__ fc_out)
{
    __shared__ __bf16 As[128 * 72];
    __shared__ __bf16 Bs[128 * 72];
    const int tid = threadIdx.x;
    const int m0 = blockIdx.x * 128, n0 = blockIdx.y * 128;
    const int wave = tid >> 6, lane = tid & 63;
    const int lr = lane & 15, lq = lane >> 4;
    const int wm = (wave & 1) * 64, wn = (wave >> 1) * 64;
    floatx4 acc[4][4] = {};

    for (int k0 = 0; k0 < 512; k0 += 64) {
        for (int i = 0; i < 4; i++) {
            int idx = tid + i * 256;
            int row = idx >> 3, c8 = (idx & 7) * 8;
            *(bf16x8*)&As[row * 72 + c8] =
                *(const bf16x8*)(ctx + (size_t)(m0 + row) * 512 + k0 + c8);
        }
        for (int i = 0; i < 8; i++) {
            int idx = tid + i * 256;
            int row = idx >> 4, c4 = (idx & 15) * 4;
            float4 w4 = *(const float4*)(Wfc + (size_t)(n0 + row) * 512 + k0 + c4);
            __bf16* db = &Bs[row * 72 + c4];
            db[0] = to_bf16(w4.x); db[1] = to_bf16(w4.y); db[2] = to_bf16(w4.z); db[3] = to_bf16(w4.w);
        }
        __syncthreads();
        for (int kk = 0; kk < 64; kk += 32) {
            bf16x8 af[4], bfr[4];
            for (int mi = 0; mi < 4; mi++)
                af[mi] = *(const bf16x8*)&As[(wm + mi * 16 + lr) * 72 + kk + lq * 8];
            for (int ni = 0; ni < 4; ni++)
                bfr[ni] = *(const bf16x8*)&Bs[(wn + ni * 16 + lr) * 72 + kk + lq * 8];
            for (int mi = 0; mi < 4; mi++)
                for (int ni = 0; ni < 4; ni++)
                    acc[mi][ni] = mfma_bf16(af[mi], bfr[ni], acc[mi][ni]);
        }
        __syncthreads();
    }

    for (int ni = 0; ni < 4; ni++) {
        int gn = n0 + wn + ni * 16 + lr;
        float bb = bfc[gn];
        for (int mi = 0; mi < 4; mi++)
            for (int r = 0; r < 4; r++) {
                int gm = m0 + wm + mi * 16 + lq * 4 + r;
                fc_out[(size_t)gm * 512 + gn] = acc[mi][ni][r] + bb;
            }
    }
}

// ---------------------------------------------------------------------------
// Kernel 4: residual add + LayerNorm. One block per row (512 cols).
// ---------------------------------------------------------------------------
__global__ __launch_bounds__(256) void ln_kernel(
    const float* __restrict__ fc_out, const float* __restrict__ qres,
    const float* __restrict__ gamma, const float* __restrict__ beta,
    float* __restrict__ y)
{
    const int row = blockIdx.x;
    const int tid = threadIdx.x;
    const size_t base = (size_t)row * 512;
    float x0 = fc_out[base + tid] + qres[base + tid];
    float x1 = fc_out[base + 256 + tid] + qres[base + 256 + tid];
    float s = x0 + x1, s2 = x0 * x0 + x1 * x1;
    for (int m = 1; m < 64; m <<= 1) { s += __shfl_xor(s, m); s2 += __shfl_xor(s2, m); }
    __shared__ float sw[4], sw2[4];
    const int wave = tid >> 6, lane = tid & 63;
    if (lane == 0) { sw[wave] = s; sw2[wave] = s2; }
    __syncthreads();
    s  = sw[0] + sw[1] + sw[2] + sw[3];
    s2 = sw2[0] + sw2[1] + sw2[2] + sw2[3];
    const float mu  = s * (1.0f / 512.0f);
    const float var = s2 * (1.0f / 512.0f) - mu * mu;
    const float rs  = rsqrtf(var + LN_EPS);
    y[base + tid]       = (x0 - mu) * rs * gamma[tid] + beta[tid];
    y[base + 256 + tid] = (x1 - mu) * rs * gamma[tid + 256] + beta[tid + 256];
}

// ---------------------------------------------------------------------------
extern "C" void kernel_launch(void* const* d_in, const int* in_sizes, int n_in,
                              void* d_out, int out_size, void* d_ws, size_t ws_size,
                              hipStream_t stream) {
    const float* q    = (const float*)d_in[0];
    const float* k    = (const float*)d_in[1];
    const float* v    = (const float*)d_in[2];
    const float* Wq   = (const float*)d_in[3];
    const float* bq   = (const float*)d_in[4];
    const float* Wk   = (const float*)d_in[5];
    const float* bk   = (const float*)d_in[6];
    const float* Wv   = (const float*)d_in[7];
    const float* bv   = (const float*)d_in[8];
    const float* Wfc  = (const float*)d_in[9];
    const float* bfc  = (const float*)d_in[10];
    const float* gam  = (const float*)d_in[11];
    const float* bet  = (const float*)d_in[12];

    float* y    = (float*)d_out;
    float* attn = y + (size_t)B_DIM * S_DIM * D_DIM;   // outputs concatenated flat

    char* ws = (char*)d_ws;
    __bf16* Qs  = (__bf16*)(ws);                         // 4 MB  [BH][S][64]
    __bf16* Ks  = (__bf16*)(ws + ((size_t)4 << 20));     // 4 MB  [BH][S][64]
    __bf16* Vt  = (__bf16*)(ws + ((size_t)8 << 20));     // 4 MB  [BH][64][S]
    __bf16* ctx = (__bf16*)(ws + ((size_t)12 << 20));    // 4 MB  [B][S][512]
    float*  fco = (float*)(ws + ((size_t)16 << 20));     // 8 MB  [4096][512]

    qkv_gemm<<<dim3(32, 4, 3), 256, 0, stream>>>(q, k, v, Wq, bq, Wk, bk, Wv, bv, Qs, Ks, Vt);
    attn_kernel<<<dim3(1024), 256, 0, stream>>>(Qs, Ks, Vt, attn, ctx);
    fc_gemm<<<dim3(32, 4), 256, 0, stream>>>(ctx, Wfc, bfc, fco);
    ln_kernel<<<dim3(4096), 256, 0, stream>>>(fco, q, gam, bet, y);
}

// Round 3
// 390.600 us; speedup vs baseline: 1.2979x; 1.2979x over previous
//
#include <hip/hip_runtime.h>
#include <hip/hip_bf16.h>
#include <cstdint>
#include <cstddef>

#define B_DIM 2
#define H_DIM 8
#define S_DIM 2048
#define D_DIM 512
#define BH_DIM 16
#define INV_TEMP 0.044194173824159216f
#define LN_EPS 1e-5f

typedef __attribute__((ext_vector_type(8))) __bf16 bf16x8;
typedef __attribute__((ext_vector_type(4))) float floatx4;

static __device__ __forceinline__ __bf16 to_bf16(float f) {
    unsigned u = __builtin_bit_cast(unsigned, f);
    u += 0x7fffu + ((u >> 16) & 1u);
    unsigned short h = (unsigned short)(u >> 16);
    return __builtin_bit_cast(__bf16, h);
}

static __device__ __forceinline__ floatx4 mfma_bf16(bf16x8 a, bf16x8 b, floatx4 c) {
    return __builtin_amdgcn_mfma_f32_16x16x32_bf16(a, b, c, 0, 0, 0);
}

// ---------------------------------------------------------------------------
// Kernel 1: QKV projections. out = x @ W^T + bias.
//   z=0: Q' = (q Wq^T + bq)/TEMP  -> Qs [BH][S][64] bf16
//   z=1: K' =  k Wk^T + bk        -> Ks [BH][S][64] bf16
//   z=2: V'^T (transposed)        -> Vt [BH][64][S] bf16
// 128x128 tile per block, BK=64, 4 waves each 64x64 (4x4 of 16x16x32 MFMA).
// ---------------------------------------------------------------------------
__global__ __launch_bounds__(256) void qkv_gemm(
    const float* __restrict__ q, const float* __restrict__ k, const float* __restrict__ v,
    const float* __restrict__ Wq, const float* __restrict__ bq,
    const float* __restrict__ Wk, const float* __restrict__ bk,
    const float* __restrict__ Wv, const float* __restrict__ bv,
    __bf16* __restrict__ Qs, __bf16* __restrict__ Ks, __bf16* __restrict__ Vt)
{
    const int z = blockIdx.z;
    const float* xin  = (z == 0) ? q  : (z == 1) ? k  : v;
    const float* W    = (z == 0) ? Wq : (z == 1) ? Wk : Wv;
    const float* bias = (z == 0) ? bq : (z == 1) ? bk : bv;

    __shared__ __bf16 As[128 * 72];   // stride 72: 144B rows -> 16B-aligned b128, 2-way banks
    __shared__ __bf16 Bs[128 * 72];

    const int tid = threadIdx.x;
    const int m0 = blockIdx.x * 128;
    const int n0 = blockIdx.y * 128;
    const int wave = tid >> 6, lane = tid & 63;
    const int lr = lane & 15, lq = lane >> 4;
    const int wm = (wave & 1) * 64, wn = (wave >> 1) * 64;

    floatx4 acc[4][4] = {};

    for (int k0 = 0; k0 < 512; k0 += 64) {
        for (int i = 0; i < 8; i++) {
            int idx = tid + i * 256;
            int row = idx >> 4, c4 = (idx & 15) * 4;
            float4 a = *(const float4*)(xin + (size_t)(m0 + row) * 512 + k0 + c4);
            __bf16* da = &As[row * 72 + c4];
            da[0] = to_bf16(a.x); da[1] = to_bf16(a.y); da[2] = to_bf16(a.z); da[3] = to_bf16(a.w);
            float4 w4 = *(const float4*)(W + (size_t)(n0 + row) * 512 + k0 + c4);
            __bf16* db = &Bs[row * 72 + c4];
            db[0] = to_bf16(w4.x); db[1] = to_bf16(w4.y); db[2] = to_bf16(w4.z); db[3] = to_bf16(w4.w);
        }
        __syncthreads();
        for (int kk = 0; kk < 64; kk += 32) {
            bf16x8 af[4], bfr[4];
            for (int mi = 0; mi < 4; mi++)
                af[mi] = *(const bf16x8*)&As[(wm + mi * 16 + lr) * 72 + kk + lq * 8];
            for (int ni = 0; ni < 4; ni++)
                bfr[ni] = *(const bf16x8*)&Bs[(wn + ni * 16 + lr) * 72 + kk + lq * 8];
            for (int mi = 0; mi < 4; mi++)
                for (int ni = 0; ni < 4; ni++)
                    acc[mi][ni] = mfma_bf16(af[mi], bfr[ni], acc[mi][ni]);
        }
        __syncthreads();
    }

    // Epilogue. D layout: row = lq*4+r, col = lr (verified m89/m91).
    for (int ni = 0; ni < 4; ni++) {
        int gn = n0 + wn + ni * 16 + lr;
        float bb = bias[gn];
        int h = gn >> 6, dd = gn & 63;
        for (int mi = 0; mi < 4; mi++) {
            for (int r = 0; r < 4; r++) {
                int gm = m0 + wm + mi * 16 + lq * 4 + r;
                int bat = gm >> 11, s = gm & 2047;
                int bh = bat * 8 + h;
                float val = acc[mi][ni][r] + bb;
                if (z == 0)      Qs[((size_t)bh * S_DIM + s) * 64 + dd] = to_bf16(val * INV_TEMP);
                else if (z == 1) Ks[((size_t)bh * S_DIM + s) * 64 + dd] = to_bf16(val);
                else             Vt[((size_t)bh * 64 + dd) * S_DIM + s] = to_bf16(val);
            }
        }
    }
}

// ---------------------------------------------------------------------------
// Kernel 2: attention, v4 — LDS-staged K/V (line-count fix).
// R0-R2 invariant: ~195us regardless of occupancy/prefetch/L2 residency.
// Diagnosis: each wave privately streamed K/V with 16-rows-per-load
// divergent addresses -> 25M 64B-line touches, saturating the per-CU
// L1 line pipe (~1 line/5cy, matches m13 copy ceiling). Fix: block = 64
// q rows, ALL 4 waves share one K-tile + one V-tile staged in LDS per
// 64-kt step (T14 async split: global->reg issued before compute,
// ds_write after barrier). 1.57 GB -> 393 MB of global reads.
// Grid 512 = 16bh x 32 qblocks, XCD-pinned (id&7 = XCD owns 2 bh).
// ---------------------------------------------------------------------------
__global__ __launch_bounds__(256, 2) void attn_kernel(
    const __bf16* __restrict__ Qs, const __bf16* __restrict__ Ks, const __bf16* __restrict__ Vt,
    float* __restrict__ attn_out, __bf16* __restrict__ ctx)
{
    // 512 blocks: xcd = id&7 (hw round-robin), j = id>>3 in [0,64):
    // bh = 2*xcd + (j>>5), qx = j&31. Bijective, 2 bh per XCD.
    const int id = blockIdx.x;
    const int xcd = id & 7, j = id >> 3;
    const int bh = (xcd << 1) | (j >> 5);
    const int qx = j & 31;
    const int b = bh >> 3, h = bh & 7;

    const int tid = threadIdx.x;
    const int wave = tid >> 6, lane = tid & 63;
    const int lr = lane & 15, lq = lane >> 4;
    const int qw = qx * 64 + wave * 16;

    const __bf16* Qh = Qs + (size_t)bh * S_DIM * 64;
    const __bf16* Kh = Ks + (size_t)bh * S_DIM * 64;
    const __bf16* Vh = Vt + (size_t)bh * 64 * S_DIM;

    __shared__ __bf16 Klds[64 * 72];    // K tile: [kpos 0..64)[d 0..64), stride 72
    __shared__ __bf16 Vlds[64 * 72];    // V tile: [d 0..64)[kpos 0..64), stride 72
    __shared__ __bf16 Pst[4][16][72];   // per-wave P tile: 16q x 64kp

    // staging coords: thread t covers rows (t>>3) and (t>>3)+32, 16B col chunk
    const int srow = tid >> 3;
    const int scol = (tid & 7) * 8;

    // Q A-frags: A[m=lr][k=lq*8+j]; held across both passes.
    bf16x8 aq0 = *(const bf16x8*)(Qh + (size_t)(qw + lr) * 64 + lq * 8);
    bf16x8 aq1 = *(const bf16x8*)(Qh + (size_t)(qw + lr) * 64 + 32 + lq * 8);

    // ==== Pass 1: row sums of exp(scores), K staged through LDS ====
    float lsum[4] = {0.f, 0.f, 0.f, 0.f};
    {
        bf16x8 k0 = *(const bf16x8*)(Kh + (size_t)srow * 64 + scol);
        bf16x8 k1 = *(const bf16x8*)(Kh + (size_t)(srow + 32) * 64 + scol);
        *(bf16x8*)&Klds[srow * 72 + scol] = k0;
        *(bf16x8*)&Klds[(srow + 32) * 72 + scol] = k1;
    }
    __syncthreads();
    for (int kt = 0; kt < S_DIM; kt += 64) {
        const int ktn = (kt + 64 < S_DIM) ? kt + 64 : kt;
        // issue next tile's loads (latency hides under compute + barrier)
        bf16x8 kn0 = *(const bf16x8*)(Kh + (size_t)(ktn + srow) * 64 + scol);
        bf16x8 kn1 = *(const bf16x8*)(Kh + (size_t)(ktn + srow + 32) * 64 + scol);
        // compute this tile from LDS
        for (int i = 0; i < 4; i++) {
            bf16x8 b0 = *(const bf16x8*)&Klds[(i * 16 + lr) * 72 + lq * 8];
            bf16x8 b1 = *(const bf16x8*)&Klds[(i * 16 + lr) * 72 + 32 + lq * 8];
            floatx4 sv = {};
            sv = mfma_bf16(aq0, b0, sv);
            sv = mfma_bf16(aq1, b1, sv);
            for (int r = 0; r < 4; r++) lsum[r] += __expf(sv[r]);
        }
        __syncthreads();
        *(bf16x8*)&Klds[srow * 72 + scol] = kn0;
        *(bf16x8*)&Klds[(srow + 32) * 72 + scol] = kn1;
        __syncthreads();
    }
    // reduce across the 16 lanes of each quad (rows are quad-local)
    for (int m = 1; m < 16; m <<= 1)
        for (int r = 0; r < 4; r++) lsum[r] += __shfl_xor(lsum[r], m);
    float linv[4];
    for (int r = 0; r < 4; r++) linv[r] = 1.0f / lsum[r];

    // ==== Pass 2: recompute scores, write normalized attn, accumulate O ====
    floatx4 o[4] = {};
    float* aout = attn_out + ((size_t)(h * B_DIM + b) * S_DIM + qw) * S_DIM;

    {
        bf16x8 k0 = *(const bf16x8*)(Kh + (size_t)srow * 64 + scol);
        bf16x8 k1 = *(const bf16x8*)(Kh + (size_t)(srow + 32) * 64 + scol);
        bf16x8 v0 = *(const bf16x8*)(Vh + (size_t)srow * S_DIM + scol);
        bf16x8 v1 = *(const bf16x8*)(Vh + (size_t)(srow + 32) * S_DIM + scol);
        *(bf16x8*)&Klds[srow * 72 + scol] = k0;
        *(bf16x8*)&Klds[(srow + 32) * 72 + scol] = k1;
        *(bf16x8*)&Vlds[srow * 72 + scol] = v0;
        *(bf16x8*)&Vlds[(srow + 32) * 72 + scol] = v1;
    }
    __syncthreads();
    for (int kt = 0; kt < S_DIM; kt += 64) {
        const int ktn = (kt + 64 < S_DIM) ? kt + 64 : kt;
        // issue next tile's K+V loads
        bf16x8 kn0 = *(const bf16x8*)(Kh + (size_t)(ktn + srow) * 64 + scol);
        bf16x8 kn1 = *(const bf16x8*)(Kh + (size_t)(ktn + srow + 32) * 64 + scol);
        bf16x8 vn0 = *(const bf16x8*)(Vh + (size_t)srow * S_DIM + ktn + scol);
        bf16x8 vn1 = *(const bf16x8*)(Vh + (size_t)(srow + 32) * S_DIM + ktn + scol);

        // QK^T + softmax-normalize + attn store + P->LDS
        for (int i = 0; i < 4; i++) {
            bf16x8 b0 = *(const bf16x8*)&Klds[(i * 16 + lr) * 72 + lq * 8];
            bf16x8 b1 = *(const bf16x8*)&Klds[(i * 16 + lr) * 72 + 32 + lq * 8];
            floatx4 sv = {};
            sv = mfma_bf16(aq0, b0, sv);
            sv = mfma_bf16(aq1, b1, sv);
            float p[4];
            for (int r = 0; r < 4; r++) p[r] = __expf(sv[r]) * linv[r];
            for (int r = 0; r < 4; r++)
                aout[(size_t)(lq * 4 + r) * S_DIM + kt + i * 16 + lr] = p[r];
            for (int r = 0; r < 4; r++)
                Pst[wave][lq * 4 + r][i * 16 + lr] = to_bf16(p[r]);
        }
        // P V (same-wave LDS round trip; compiler inserts lgkmcnt)
        for (int ks = 0; ks < 2; ks++) {
            bf16x8 pa = *(const bf16x8*)&Pst[wave][lr][ks * 32 + lq * 8];
            for (int ni = 0; ni < 4; ni++) {
                bf16x8 vb = *(const bf16x8*)&Vlds[(ni * 16 + lr) * 72 + ks * 32 + lq * 8];
                o[ni] = mfma_bf16(pa, vb, o[ni]);
            }
        }
        __syncthreads();
        *(bf16x8*)&Klds[srow * 72 + scol] = kn0;
        *(bf16x8*)&Klds[(srow + 32) * 72 + scol] = kn1;
        *(bf16x8*)&Vlds[srow * 72 + scol] = vn0;
        *(bf16x8*)&Vlds[(srow + 32) * 72 + scol] = vn1;
        __syncthreads();
    }

    // ctx[b][s][h*64+d] merged-head context, bf16
    for (int ni = 0; ni < 4; ni++)
        for (int r = 0; r < 4; r++)
            ctx[((size_t)b * S_DIM + qw + lq * 4 + r) * 512 + h * 64 + ni * 16 + lr] =
                to_bf16(o[ni][r]);
}

// ---------------------------------------------------------------------------
// Kernel 3: fc projection. fc_out = ctx @ Wfc^T + bfc (fp32 to ws).
// ---------------------------------------------------------------------------
__global__ __launch_bounds__(256) void fc_gemm(
    const __bf16* __restrict__ ctx, const float* __restrict__ Wfc,
    const float* __restrict__ bfc, float* __restrict__ fc_out)
{
    __shared__ __bf16 As[128 * 72];
    __shared__ __bf16 Bs[128 * 72];
    const int tid = threadIdx.x;
    const int m0 = blockIdx.x * 128, n0 = blockIdx.y * 128;
    const int wave = tid >> 6, lane = tid & 63;
    const int lr = lane & 15, lq = lane >> 4;
    const int wm = (wave & 1) * 64, wn = (wave >> 1) * 64;
    floatx4 acc[4][4] = {};

    for (int k0 = 0; k0 < 512; k0 += 64) {
        for (int i = 0; i < 4; i++) {
            int idx = tid + i * 256;
            int row = idx >> 3, c8 = (idx & 7) * 8;
            *(bf16x8*)&As[row * 72 + c8] =
                *(const bf16x8*)(ctx + (size_t)(m0 + row) * 512 + k0 + c8);
        }
        for (int i = 0; i < 8; i++) {
            int idx = tid + i * 256;
            int row = idx >> 4, c4 = (idx & 15) * 4;
            float4 w4 = *(const float4*)(Wfc + (size_t)(n0 + row) * 512 + k0 + c4);
            __bf16* db = &Bs[row * 72 + c4];
            db[0] = to_bf16(w4.x); db[1] = to_bf16(w4.y); db[2] = to_bf16(w4.z); db[3] = to_bf16(w4.w);
        }
        __syncthreads();
        for (int kk = 0; kk < 64; kk += 32) {
            bf16x8 af[4], bfr[4];
            for (int mi = 0; mi < 4; mi++)
                af[mi] = *(const bf16x8*)&As[(wm + mi * 16 + lr) * 72 + kk + lq * 8];
            for (int ni = 0; ni < 4; ni++)
                bfr[ni] = *(const bf16x8*)&Bs[(wn + ni * 16 + lr) * 72 + kk + lq * 8];
            for (int mi = 0; mi < 4; mi++)
                for (int ni = 0; ni < 4; ni++)
                    acc[mi][ni] = mfma_bf16(af[mi], bfr[ni], acc[mi][ni]);
        }
        __syncthreads();
    }

    for (int ni = 0; ni < 4; ni++) {
        int gn = n0 + wn + ni * 16 + lr;
        float bb = bfc[gn];
        for (int mi = 0; mi < 4; mi++)
            for (int r = 0; r < 4; r++) {
                int gm = m0 + wm + mi * 16 + lq * 4 + r;
                fc_out[(size_t)gm * 512 + gn] = acc[mi][ni][r] + bb;
            }
    }
}

// ---------------------------------------------------------------------------
// Kernel 4: residual add + LayerNorm. One block per row (512 cols).
// ---------------------------------------------------------------------------
__global__ __launch_bounds__(256) void ln_kernel(
    const float* __restrict__ fc_out, const float* __restrict__ qres,
    const float* __restrict__ gamma, const float* __restrict__ beta,
    float* __restrict__ y)
{
    const int row = blockIdx.x;
    const int tid = threadIdx.x;
    const size_t base = (size_t)row * 512;
    float x0 = fc_out[base + tid] + qres[base + tid];
    float x1 = fc_out[base + 256 + tid] + qres[base + 256 + tid];
    float s = x0 + x1, s2 = x0 * x0 + x1 * x1;
    for (int m = 1; m < 64; m <<= 1) { s += __shfl_xor(s, m); s2 += __shfl_xor(s2, m); }
    __shared__ float sw[4], sw2[4];
    const int wave = tid >> 6, lane = tid & 63;
    if (lane == 0) { sw[wave] = s; sw2[wave] = s2; }
    __syncthreads();
    s  = sw[0] + sw[1] + sw[2] + sw[3];
    s2 = sw2[0] + sw2[1] + sw2[2] + sw2[3];
    const float mu  = s * (1.0f / 512.0f);
    const float var = s2 * (1.0f / 512.0f) - mu * mu;
    const float rs  = rsqrtf(var + LN_EPS);
    y[base + tid]       = (x0 - mu) * rs * gamma[tid] + beta[tid];
    y[base + 256 + tid] = (x1 - mu) * rs * gamma[tid + 256] + beta[tid + 256];
}

// ---------------------------------------------------------------------------
extern "C" void kernel_launch(void* const* d_in, const int* in_sizes, int n_in,
                              void* d_out, int out_size, void* d_ws, size_t ws_size,
                              hipStream_t stream) {
    const float* q    = (const float*)d_in[0];
    const float* k    = (const float*)d_in[1];
    const float* v    = (const float*)d_in[2];
    const float* Wq   = (const float*)d_in[3];
    const float* bq   = (const float*)d_in[4];
    const float* Wk   = (const float*)d_in[5];
    const float* bk   = (const float*)d_in[6];
    const float* Wv   = (const float*)d_in[7];
    const float* bv   = (const float*)d_in[8];
    const float* Wfc  = (const float*)d_in[9];
    const float* bfc  = (const float*)d_in[10];
    const float* gam  = (const float*)d_in[11];
    const float* bet  = (const float*)d_in[12];

    float* y    = (float*)d_out;
    float* attn = y + (size_t)B_DIM * S_DIM * D_DIM;   // outputs concatenated flat

    char* ws = (char*)d_ws;
    __bf16* Qs  = (__bf16*)(ws);                         // 4 MB  [BH][S][64]
    __bf16* Ks  = (__bf16*)(ws + ((size_t)4 << 20));     // 4 MB  [BH][S][64]
    __bf16* Vt  = (__bf16*)(ws + ((size_t)8 << 20));     // 4 MB  [BH][64][S]
    __bf16* ctx = (__bf16*)(ws + ((size_t)12 << 20));    // 4 MB  [B][S][512]
    float*  fco = (float*)(ws + ((size_t)16 << 20));     // 8 MB  [4096][512]

    qkv_gemm<<<dim3(32, 4, 3), 256, 0, stream>>>(q, k, v, Wq, bq, Wk, bk, Wv, bv, Qs, Ks, Vt);
    attn_kernel<<<dim3(512), 256, 0, stream>>>(Qs, Ks, Vt, attn, ctx);
    fc_gemm<<<dim3(32, 4), 256, 0, stream>>>(ctx, Wfc, bfc, fco);
    ln_kernel<<<dim3(4096), 256, 0, stream>>>(fco, q, gam, bet, y);
}